// Round 3
// baseline (522.675 us; speedup 1.0000x reference)
//
#include <hip/hip_runtime.h>

// DeepSeek MoE (N=2048, D=768, I=3072, E=8, K=2 + shared expert), fp32 in/out,
// bf16 MFMA compute. R3: BN=128/weight fused act-GEMM with XOR-swizzled LDS
// (conflict-free b128 fragment reads), gather fused into global_load_lds
// staging, split-K=4 out-GEMM with bf16 partials, all prep in one launch.

#define D_ 768
#define I_ 3072
#define E_ 8
#define NTOK 2048
#define NPMAX 5120          // 4096 pairs + worst-case 128-padding per expert
#define MAXTILES 40
#define NSHT 16             // shared-expert M tiles: 2048/128
#define SPLITK 4
#define KS_ (I_ / SPLITK)   // 768

typedef __bf16 bf16x8 __attribute__((ext_vector_type(8)));
typedef float floatx4 __attribute__((ext_vector_type(4)));

#define GLOAD_LDS16(g, l) __builtin_amdgcn_global_load_lds( \
    (const __attribute__((address_space(1))) void*)(g),     \
    (__attribute__((address_space(3))) void*)(l), 16, 0, 0)

__device__ __forceinline__ unsigned short f2b(float f) {
    unsigned int u = __float_as_uint(f);
    u += 0x7fffu + ((u >> 16) & 1u);          // RNE to bf16
    return (unsigned short)(u >> 16);
}
__device__ __forceinline__ float b2f(unsigned short u) {
    return __uint_as_float((unsigned int)u << 16);
}

// ---------------- prep: all transposes + cast_x + gating, one launch --------
// blocks [0,10368): 18 z-slabs of [768][3072] -> bf16 [3072][768]
// blocks [10368,15552): 9 z-slabs of [3072][768] -> bf16 [768][3072]
// blocks [15552,17088): cast x -> bf16
// blocks [17088,17600): gating (4 tokens per block, one wave each)

__global__ __launch_bounds__(256) void prep_kernel(
    const float* __restrict__ x, const float* __restrict__ gw,
    const float* __restrict__ gbias,
    const float* __restrict__ w1, const float* __restrict__ w2,
    const float* __restrict__ w3, const float* __restrict__ w1s,
    const float* __restrict__ w2s, const float* __restrict__ w3s,
    unsigned short* __restrict__ xb,
    unsigned short* __restrict__ w1b, unsigned short* __restrict__ w3b,
    unsigned short* __restrict__ w2b, unsigned short* __restrict__ w1sb,
    unsigned short* __restrict__ w3sb, unsigned short* __restrict__ w2sb,
    int* __restrict__ idx, float* __restrict__ wts) {
    __shared__ float t[64][65];
    int b = blockIdx.x, tid = threadIdx.x;
    if (b < 15552) {
        const float* s; unsigned short* d; int R, C, bx, by;
        if (b < 10368) {
            int z = b / 576, r = b % 576; bx = r % 48; by = r / 48; R = D_; C = I_;
            if (z < 8)       { s = w1 + (size_t)z * D_ * I_;       d = w1b + (size_t)z * D_ * I_; }
            else if (z < 16) { s = w3 + (size_t)(z - 8) * D_ * I_; d = w3b + (size_t)(z - 8) * D_ * I_; }
            else if (z == 16){ s = w1s; d = w1sb; }
            else             { s = w3s; d = w3sb; }
        } else {
            int bb = b - 10368;
            int z = bb / 576, r = bb % 576; bx = r % 12; by = r / 12; R = I_; C = D_;
            if (z < 8) { s = w2 + (size_t)z * I_ * D_; d = w2b + (size_t)z * I_ * D_; }
            else       { s = w2s; d = w2sb; }
        }
        int c0 = bx * 64, r0 = by * 64;
#pragma unroll
        for (int j = 0; j < 4; j++) {
            int slot = tid + j * 256;
            int rr = slot >> 4, c4 = (slot & 15) * 4;
            float4 v = *(const float4*)(s + (size_t)(r0 + rr) * C + c0 + c4);
            t[rr][c4] = v.x; t[rr][c4 + 1] = v.y; t[rr][c4 + 2] = v.z; t[rr][c4 + 3] = v.w;
        }
        __syncthreads();
#pragma unroll
        for (int j = 0; j < 2; j++) {
            int slot = tid + j * 256;
            int c = slot >> 3, rs = (slot & 7) * 8;
            unsigned short o[8] __attribute__((aligned(16)));
#pragma unroll
            for (int i = 0; i < 8; i++) o[i] = f2b(t[rs + i][c]);
            *(int4*)(d + (size_t)(c0 + c) * R + r0 + rs) = *(const int4*)o;
        }
    } else if (b < 17088) {
        int gid = (b - 15552) * 256 + tid;
        float4 v = *(const float4*)(x + (size_t)gid * 4);
        ushort4 o;
        o.x = f2b(v.x); o.y = f2b(v.y); o.z = f2b(v.z); o.w = f2b(v.w);
        *(ushort4*)(xb + (size_t)gid * 4) = o;
    } else {
        int tok = (b - 17088) * 4 + (tid >> 6);
        int lane = tid & 63;
        float z[E_];
#pragma unroll
        for (int e = 0; e < E_; e++) z[e] = 0.f;
        const float* xr = x + (size_t)tok * D_;
        for (int j = lane; j < D_; j += 64) {
            float xv = xr[j];
            const float* g = gw + (size_t)j * E_;
#pragma unroll
            for (int e = 0; e < E_; e++) z[e] += xv * g[e];
        }
#pragma unroll
        for (int off = 32; off > 0; off >>= 1)
#pragma unroll
            for (int e = 0; e < E_; e++) z[e] += __shfl_down(z[e], off, 64);
        if (lane == 0) {
            float s[E_], r[E_];
#pragma unroll
            for (int e = 0; e < E_; e++) {
                float zz = z[e];
                float sp = zz > 0.f ? zz + log1pf(expf(-zz)) : log1pf(expf(zz));
                s[e] = sqrtf(sp);
                r[e] = s[e] + gbias[e];
            }
            int i0 = 0;
            for (int e = 1; e < E_; e++) if (r[e] > r[i0]) i0 = e;
            int i1 = (i0 == 0) ? 1 : 0;
            for (int e = 0; e < E_; e++) if (e != i0 && r[e] > r[i1]) i1 = e;
            float w0 = s[i0], w1v = s[i1];
            float inv = 1.f / fmaxf(w0 + w1v, 1e-6f);
            idx[2 * tok] = i0; idx[2 * tok + 1] = i1;
            wts[2 * tok] = w0 * inv; wts[2 * tok + 1] = w1v * inv;
        }
    }
}

// ---------------- routing build (single block) ----------------

__global__ void route_build_kernel(const int* __restrict__ idx,
                                   const float* __restrict__ wts,
                                   int* __restrict__ pair_token,
                                   float* __restrict__ pair_w,
                                   int* __restrict__ pos_of,
                                   int* __restrict__ tiles) {
    __shared__ int cnt[E_], seg[E_], cur[E_];
    int tid = threadIdx.x;
    if (tid < E_) { cnt[tid] = 0; cur[tid] = 0; }
    __syncthreads();
    for (int p = tid; p < NTOK * 2; p += 256) atomicAdd(&cnt[idx[p]], 1);
    __syncthreads();
    if (tid == 0) {
        int off = 0, nt = 0;
        for (int e = 0; e < E_; e++) {
            seg[e] = off;
            int te = (cnt[e] + 127) >> 7;
            for (int j = 0; j < te; j++) {
                tiles[nt * 2] = e; tiles[nt * 2 + 1] = off + j * 128; nt++;
            }
            off += te * 128;
        }
        for (; nt < MAXTILES; nt++) { tiles[nt * 2] = -1; tiles[nt * 2 + 1] = 0; }
    }
    for (int p = tid; p < NPMAX; p += 256) pair_token[p] = -1;
    __syncthreads();
    for (int p = tid; p < NTOK * 2; p += 256) {
        int e = idx[p];
        int r = atomicAdd(&cur[e], 1);
        int pos = seg[e] + r;
        pair_token[pos] = p >> 1;
        pair_w[pos] = wts[p];
        pos_of[p] = pos;
    }
}

// ---------------- GEMM 1: fused gate/up + activation ----------------
// BM=128, BN=128 per weight, BK=32. XOR-swizzled chunk staging; gather fused
// via per-lane global_load_lds source addresses. 4 waves, 64x64/weight each.

__launch_bounds__(256)
__global__ void gemm_act_kernel(const unsigned short* __restrict__ xb,
                                const unsigned short* __restrict__ w1sb,
                                const unsigned short* __restrict__ w3sb,
                                const unsigned short* __restrict__ w1b,
                                const unsigned short* __restrict__ w3b,
                                const int* __restrict__ tiles,
                                const int* __restrict__ pair_token,
                                unsigned short* __restrict__ act_s,
                                unsigned short* __restrict__ act_r) {
    __shared__ __align__(16) unsigned short As[128 * 32];
    __shared__ __align__(16) unsigned short Bs1[128 * 32];
    __shared__ __align__(16) unsigned short Bs3[128 * 32];

    int mt = blockIdx.y;
    const unsigned short *B1, *B3;
    unsigned short* C;
    int m0; bool routed;
    if (mt < NSHT) {
        B1 = w1sb; B3 = w3sb; C = act_s; m0 = mt * 128; routed = false;
    } else {
        int e = tiles[(mt - NSHT) * 2];
        if (e < 0) return;
        m0 = tiles[(mt - NSHT) * 2 + 1];
        B1 = w1b + (size_t)e * I_ * D_; B3 = w3b + (size_t)e * I_ * D_;
        C = act_r; routed = true;
    }
    int n0 = blockIdx.x * 128;
    int tid = threadIdx.x;
    int lane = tid & 63, wave = tid >> 6;
    int wm = (wave & 1) * 64, wn = (wave >> 1) * 64;
    int l15 = lane & 15, quad = lane >> 4;

    // staging: thread t -> row r=t>>2, physical chunk t&3 holds logical chunk
    // lc = (t&3) ^ ((r>>1)&3)  (XOR swizzle kills b128 read conflicts)
    int r = tid >> 2;
    int lc8 = (((tid & 3) ^ ((r >> 1) & 3)) * 8);
    int tokA0, tokA1;
    if (routed) {
        tokA0 = pair_token[m0 + r];      if (tokA0 < 0) tokA0 = 0;
        tokA1 = pair_token[m0 + r + 64]; if (tokA1 < 0) tokA1 = 0;
    } else { tokA0 = m0 + r; tokA1 = m0 + r + 64; }
    const unsigned short* ApA0 = xb + (size_t)tokA0 * D_ + lc8;
    const unsigned short* ApA1 = xb + (size_t)tokA1 * D_ + lc8;
    const unsigned short* B1p0 = B1 + (size_t)(n0 + r) * D_ + lc8;
    const unsigned short* B1p1 = B1 + (size_t)(n0 + r + 64) * D_ + lc8;
    const unsigned short* B3p0 = B3 + (size_t)(n0 + r) * D_ + lc8;
    const unsigned short* B3p1 = B3 + (size_t)(n0 + r + 64) * D_ + lc8;
    unsigned short* lA0  = As  + wave * 512;
    unsigned short* lA1  = As  + 2048 + wave * 512;
    unsigned short* lB10 = Bs1 + wave * 512;
    unsigned short* lB11 = Bs1 + 2048 + wave * 512;
    unsigned short* lB30 = Bs3 + wave * 512;
    unsigned short* lB31 = Bs3 + 2048 + wave * 512;

    int swz = (quad ^ ((l15 >> 1) & 3)) * 8;   // fragment-read chunk position
    floatx4 acc1[4][4] = {}; floatx4 acc3[4][4] = {};

    for (int k0 = 0; k0 < D_; k0 += 32) {
        __syncthreads();
        GLOAD_LDS16(ApA0 + k0, lA0);
        GLOAD_LDS16(ApA1 + k0, lA1);
        GLOAD_LDS16(B1p0 + k0, lB10);
        GLOAD_LDS16(B1p1 + k0, lB11);
        GLOAD_LDS16(B3p0 + k0, lB30);
        GLOAD_LDS16(B3p1 + k0, lB31);
        __syncthreads();

        bf16x8 af[4], b1f[4], b3f[4];
#pragma unroll
        for (int mi = 0; mi < 4; mi++)
            af[mi] = *(const bf16x8*)(As + (wm + mi * 16 + l15) * 32 + swz);
#pragma unroll
        for (int ni = 0; ni < 4; ni++) {
            b1f[ni] = *(const bf16x8*)(Bs1 + (wn + ni * 16 + l15) * 32 + swz);
            b3f[ni] = *(const bf16x8*)(Bs3 + (wn + ni * 16 + l15) * 32 + swz);
        }
#pragma unroll
        for (int mi = 0; mi < 4; mi++)
#pragma unroll
            for (int ni = 0; ni < 4; ni++) {
                acc1[mi][ni] = __builtin_amdgcn_mfma_f32_16x16x32_bf16(
                    af[mi], b1f[ni], acc1[mi][ni], 0, 0, 0);
                acc3[mi][ni] = __builtin_amdgcn_mfma_f32_16x16x32_bf16(
                    af[mi], b3f[ni], acc3[mi][ni], 0, 0, 0);
            }
    }

#pragma unroll
    for (int mi = 0; mi < 4; mi++)
#pragma unroll
        for (int ni = 0; ni < 4; ni++) {
            int col = n0 + wn + ni * 16 + l15;
#pragma unroll
            for (int rr = 0; rr < 4; rr++) {
                int row = m0 + wm + mi * 16 + quad * 4 + rr;
                float g = fminf(acc1[mi][ni][rr], 10.f);
                float u = fminf(fmaxf(acc3[mi][ni][rr], -10.f), 10.f);
                float a = g / (1.f + __expf(-g)) * u;
                C[(size_t)row * I_ + col] = f2b(a);
            }
        }
}

// ---------------- GEMM 2: act @ W2, split-K=4, bf16 partials ----------------

__launch_bounds__(256)
__global__ void gemm_out_kernel(const unsigned short* __restrict__ act_s,
                                const unsigned short* __restrict__ act_r,
                                const unsigned short* __restrict__ w2sb,
                                const unsigned short* __restrict__ w2b,
                                const int* __restrict__ tiles,
                                unsigned short* __restrict__ ysp,
                                unsigned short* __restrict__ rop) {
    __shared__ __align__(16) unsigned short As[128 * 32];
    __shared__ __align__(16) unsigned short Bs[128 * 32];

    int mt = blockIdx.y, ks = blockIdx.z;
    int kbase = ks * KS_;
    const unsigned short *A, *B;
    unsigned short* C;
    int m0;
    if (mt < NSHT) {
        A = act_s; B = w2sb; C = ysp + (size_t)ks * NTOK * D_; m0 = mt * 128;
    } else {
        int e = tiles[(mt - NSHT) * 2];
        if (e < 0) return;
        m0 = tiles[(mt - NSHT) * 2 + 1];
        A = act_r; B = w2b + (size_t)e * I_ * D_; C = rop + (size_t)ks * NPMAX * D_;
    }
    int n0 = blockIdx.x * 128;
    int tid = threadIdx.x;
    int lane = tid & 63, wave = tid >> 6;
    int wm = (wave & 1) * 64, wn = (wave >> 1) * 64;
    int l15 = lane & 15, quad = lane >> 4;

    int r = tid >> 2;
    int lc8 = (((tid & 3) ^ ((r >> 1) & 3)) * 8);
    const unsigned short* Ap0 = A + (size_t)(m0 + r) * I_ + kbase + lc8;
    const unsigned short* Ap1 = A + (size_t)(m0 + r + 64) * I_ + kbase + lc8;
    const unsigned short* Bp0 = B + (size_t)(n0 + r) * I_ + kbase + lc8;
    const unsigned short* Bp1 = B + (size_t)(n0 + r + 64) * I_ + kbase + lc8;
    unsigned short* lA0 = As + wave * 512;
    unsigned short* lA1 = As + 2048 + wave * 512;
    unsigned short* lB0 = Bs + wave * 512;
    unsigned short* lB1 = Bs + 2048 + wave * 512;

    int swz = (quad ^ ((l15 >> 1) & 3)) * 8;
    floatx4 acc[4][4] = {};

    for (int k0 = 0; k0 < KS_; k0 += 32) {
        __syncthreads();
        GLOAD_LDS16(Ap0 + k0, lA0);
        GLOAD_LDS16(Ap1 + k0, lA1);
        GLOAD_LDS16(Bp0 + k0, lB0);
        GLOAD_LDS16(Bp1 + k0, lB1);
        __syncthreads();

        bf16x8 af[4], bf[4];
#pragma unroll
        for (int mi = 0; mi < 4; mi++)
            af[mi] = *(const bf16x8*)(As + (wm + mi * 16 + l15) * 32 + swz);
#pragma unroll
        for (int ni = 0; ni < 4; ni++)
            bf[ni] = *(const bf16x8*)(Bs + (wn + ni * 16 + l15) * 32 + swz);
#pragma unroll
        for (int mi = 0; mi < 4; mi++)
#pragma unroll
            for (int ni = 0; ni < 4; ni++)
                acc[mi][ni] = __builtin_amdgcn_mfma_f32_16x16x32_bf16(
                    af[mi], bf[ni], acc[mi][ni], 0, 0, 0);
    }

#pragma unroll
    for (int mi = 0; mi < 4; mi++)
#pragma unroll
        for (int ni = 0; ni < 4; ni++) {
            int col = n0 + wn + ni * 16 + l15;
#pragma unroll
            for (int rr = 0; rr < 4; rr++) {
                int row = m0 + wm + mi * 16 + quad * 4 + rr;
                C[(size_t)row * D_ + col] = f2b(acc[mi][ni][rr]);
            }
        }
}

// ---------------- combine: sum split-K partials + weighted routed -----------

__global__ void combine_kernel(const unsigned short* __restrict__ ysp,
                               const unsigned short* __restrict__ rop,
                               const int* __restrict__ pos_of,
                               const float* __restrict__ pair_w,
                               float* __restrict__ out) {
    int gid = blockIdx.x * 256 + threadIdx.x;
    int t = gid / (D_ / 4);
    int j = (gid % (D_ / 4)) * 4;
    int p0 = pos_of[2 * t], p1 = pos_of[2 * t + 1];
    float w0 = pair_w[p0], w1 = pair_w[p1];
    float a0 = 0.f, a1 = 0.f, a2 = 0.f, a3 = 0.f;
#pragma unroll
    for (int ks = 0; ks < SPLITK; ks++) {
        ushort4 a = *(const ushort4*)(ysp + ((size_t)ks * NTOK + t) * D_ + j);
        ushort4 b = *(const ushort4*)(rop + ((size_t)ks * NPMAX + p0) * D_ + j);
        ushort4 c = *(const ushort4*)(rop + ((size_t)ks * NPMAX + p1) * D_ + j);
        a0 += b2f(a.x) + w0 * b2f(b.x) + w1 * b2f(c.x);
        a1 += b2f(a.y) + w0 * b2f(b.y) + w1 * b2f(c.y);
        a2 += b2f(a.z) + w0 * b2f(b.z) + w1 * b2f(c.z);
        a3 += b2f(a.w) + w0 * b2f(b.w) + w1 * b2f(c.w);
    }
    float4 o; o.x = a0; o.y = a1; o.z = a2; o.w = a3;
    *(float4*)(out + (size_t)t * D_ + j) = o;
}

// ---------------- launch ----------------

extern "C" void kernel_launch(void* const* d_in, const int* in_sizes, int n_in,
                              void* d_out, int out_size, void* d_ws, size_t ws_size,
                              hipStream_t stream) {
    (void)in_sizes; (void)n_in; (void)out_size; (void)ws_size;
    const float* x   = (const float*)d_in[0];
    const float* gw  = (const float*)d_in[2];
    const float* gb  = (const float*)d_in[3];
    const float* w1  = (const float*)d_in[4];
    const float* w2  = (const float*)d_in[5];
    const float* w3  = (const float*)d_in[6];
    const float* w1s = (const float*)d_in[7];
    const float* w2s = (const float*)d_in[8];
    const float* w3s = (const float*)d_in[9];
    float* out = (float*)d_out;

    char* ws = (char*)d_ws;
    size_t off = 0;
    auto alloc = [&](size_t bytes) {
        size_t o = (off + 255) & ~(size_t)255;
        off = o + bytes;
        return (void*)(ws + o);
    };
    unsigned short* xb   = (unsigned short*)alloc((size_t)NTOK * D_ * 2);
    unsigned short* w1b  = (unsigned short*)alloc((size_t)E_ * I_ * D_ * 2);
    unsigned short* w3b  = (unsigned short*)alloc((size_t)E_ * I_ * D_ * 2);
    unsigned short* w2b  = (unsigned short*)alloc((size_t)E_ * I_ * D_ * 2);
    unsigned short* w1sb = (unsigned short*)alloc((size_t)I_ * D_ * 2);
    unsigned short* w3sb = (unsigned short*)alloc((size_t)I_ * D_ * 2);
    unsigned short* w2sb = (unsigned short*)alloc((size_t)I_ * D_ * 2);
    unsigned short* acts = (unsigned short*)alloc((size_t)NTOK * I_ * 2);
    unsigned short* actr = (unsigned short*)alloc((size_t)NPMAX * I_ * 2);
    unsigned short* ysp  = (unsigned short*)alloc((size_t)SPLITK * NTOK * D_ * 2);
    unsigned short* rop  = (unsigned short*)alloc((size_t)SPLITK * NPMAX * D_ * 2);
    int*   idx  = (int*)alloc((size_t)NTOK * 2 * 4);
    float* wts  = (float*)alloc((size_t)NTOK * 2 * 4);
    int*   ptok = (int*)alloc((size_t)NPMAX * 4);
    float* pw   = (float*)alloc((size_t)NPMAX * 4);
    int*   posf = (int*)alloc((size_t)NTOK * 2 * 4);
    int*   tls  = (int*)alloc((size_t)MAXTILES * 2 * 4);

    prep_kernel<<<17600, 256, 0, stream>>>(x, gw, gb, w1, w2, w3, w1s, w2s, w3s,
                                           xb, w1b, w3b, w2b, w1sb, w3sb, w2sb,
                                           idx, wts);
    route_build_kernel<<<1, 256, 0, stream>>>(idx, wts, ptok, pw, posf, tls);
    gemm_act_kernel<<<dim3(I_ / 128, NSHT + MAXTILES), 256, 0, stream>>>(
        xb, w1sb, w3sb, w1b, w3b, tls, ptok, acts, actr);
    gemm_out_kernel<<<dim3(D_ / 128, NSHT + MAXTILES, SPLITK), 256, 0, stream>>>(
        acts, actr, w2sb, w2b, tls, ysp, rop);
    combine_kernel<<<NTOK * (D_ / 4) / 256, 256, 0, stream>>>(ysp, rop, posf, pw, out);
}

// Round 4
// 467.108 us; speedup vs baseline: 1.1190x; 1.1190x over previous
//
#include <hip/hip_runtime.h>

// DeepSeek MoE (N=2048, D=768, I=3072, E=8, K=2 + shared expert), fp32 in/out,
// bf16 MFMA compute. R4: R2 tile geometry (acc=64 -> 3 waves/SIMD) + XOR
// swizzle (conflict-free LDS) + fused gather + BK=64 (half the barriers);
// unified row space; split-K=2 out-GEMM with fp32 partials.

#define D_ 768
#define I_ 3072
#define E_ 8
#define NTOK 2048
#define NPMAX 5120          // 4096 pairs + worst-case 128-padding per expert
#define MAXTILES 40
#define NSHT 16             // shared-expert M tiles: 2048/128
#define ROWS (NTOK + NPMAX) // unified act/out rows
#define SPLITK 2
#define KS_ (I_ / SPLITK)   // 1536

typedef __bf16 bf16x8 __attribute__((ext_vector_type(8)));
typedef float floatx4 __attribute__((ext_vector_type(4)));

#define GLOAD_LDS16(g, l) __builtin_amdgcn_global_load_lds( \
    (const __attribute__((address_space(1))) void*)(g),     \
    (__attribute__((address_space(3))) void*)(l), 16, 0, 0)

__device__ __forceinline__ unsigned short f2b(float f) {
    unsigned int u = __float_as_uint(f);
    u += 0x7fffu + ((u >> 16) & 1u);          // RNE to bf16
    return (unsigned short)(u >> 16);
}

// ---------------- prep: all transposes + cast_x + gating, one launch --------

__global__ __launch_bounds__(256) void prep_kernel(
    const float* __restrict__ x, const float* __restrict__ gw,
    const float* __restrict__ gbias,
    const float* __restrict__ w1, const float* __restrict__ w2,
    const float* __restrict__ w3, const float* __restrict__ w1s,
    const float* __restrict__ w2s, const float* __restrict__ w3s,
    unsigned short* __restrict__ xb,
    unsigned short* __restrict__ w1b, unsigned short* __restrict__ w3b,
    unsigned short* __restrict__ w2b, unsigned short* __restrict__ w1sb,
    unsigned short* __restrict__ w3sb, unsigned short* __restrict__ w2sb,
    int* __restrict__ idx, float* __restrict__ wts) {
    __shared__ float t[64][65];
    int b = blockIdx.x, tid = threadIdx.x;
    if (b < 15552) {
        const float* s; unsigned short* d; int R, C, bx, by;
        if (b < 10368) {
            int z = b / 576, r = b % 576; bx = r % 48; by = r / 48; R = D_; C = I_;
            if (z < 8)       { s = w1 + (size_t)z * D_ * I_;       d = w1b + (size_t)z * D_ * I_; }
            else if (z < 16) { s = w3 + (size_t)(z - 8) * D_ * I_; d = w3b + (size_t)(z - 8) * D_ * I_; }
            else if (z == 16){ s = w1s; d = w1sb; }
            else             { s = w3s; d = w3sb; }
        } else {
            int bb = b - 10368;
            int z = bb / 576, r = bb % 576; bx = r % 12; by = r / 12; R = I_; C = D_;
            if (z < 8) { s = w2 + (size_t)z * I_ * D_; d = w2b + (size_t)z * I_ * D_; }
            else       { s = w2s; d = w2sb; }
        }
        int c0 = bx * 64, r0 = by * 64;
#pragma unroll
        for (int j = 0; j < 4; j++) {
            int slot = tid + j * 256;
            int rr = slot >> 4, c4 = (slot & 15) * 4;
            float4 v = *(const float4*)(s + (size_t)(r0 + rr) * C + c0 + c4);
            t[rr][c4] = v.x; t[rr][c4 + 1] = v.y; t[rr][c4 + 2] = v.z; t[rr][c4 + 3] = v.w;
        }
        __syncthreads();
#pragma unroll
        for (int j = 0; j < 2; j++) {
            int slot = tid + j * 256;
            int c = slot >> 3, rs = (slot & 7) * 8;
            unsigned short o[8] __attribute__((aligned(16)));
#pragma unroll
            for (int i = 0; i < 8; i++) o[i] = f2b(t[rs + i][c]);
            *(int4*)(d + (size_t)(c0 + c) * R + r0 + rs) = *(const int4*)o;
        }
    } else if (b < 17088) {
        int gid = (b - 15552) * 256 + tid;
        float4 v = *(const float4*)(x + (size_t)gid * 4);
        ushort4 o;
        o.x = f2b(v.x); o.y = f2b(v.y); o.z = f2b(v.z); o.w = f2b(v.w);
        *(ushort4*)(xb + (size_t)gid * 4) = o;
    } else {
        int tok = (b - 17088) * 4 + (tid >> 6);
        int lane = tid & 63;
        float z[E_];
#pragma unroll
        for (int e = 0; e < E_; e++) z[e] = 0.f;
        const float* xr = x + (size_t)tok * D_;
        for (int j = lane; j < D_; j += 64) {
            float xv = xr[j];
            const float* g = gw + (size_t)j * E_;
#pragma unroll
            for (int e = 0; e < E_; e++) z[e] += xv * g[e];
        }
#pragma unroll
        for (int off = 32; off > 0; off >>= 1)
#pragma unroll
            for (int e = 0; e < E_; e++) z[e] += __shfl_down(z[e], off, 64);
        if (lane == 0) {
            float s[E_], r[E_];
#pragma unroll
            for (int e = 0; e < E_; e++) {
                float zz = z[e];
                float sp = zz > 0.f ? zz + log1pf(expf(-zz)) : log1pf(expf(zz));
                s[e] = sqrtf(sp);
                r[e] = s[e] + gbias[e];
            }
            int i0 = 0;
            for (int e = 1; e < E_; e++) if (r[e] > r[i0]) i0 = e;
            int i1 = (i0 == 0) ? 1 : 0;
            for (int e = 0; e < E_; e++) if (e != i0 && r[e] > r[i1]) i1 = e;
            float w0 = s[i0], w1v = s[i1];
            float inv = 1.f / fmaxf(w0 + w1v, 1e-6f);
            idx[2 * tok] = i0; idx[2 * tok + 1] = i1;
            wts[2 * tok] = w0 * inv; wts[2 * tok + 1] = w1v * inv;
        }
    }
}

// ---------------- routing build (single block) ----------------

__global__ void route_build_kernel(const int* __restrict__ idx,
                                   const float* __restrict__ wts,
                                   int* __restrict__ pair_token,
                                   float* __restrict__ pair_w,
                                   int* __restrict__ pos_of,
                                   int* __restrict__ tiles) {
    __shared__ int cnt[E_], seg[E_], cur[E_];
    int tid = threadIdx.x;
    if (tid < E_) { cnt[tid] = 0; cur[tid] = 0; }
    __syncthreads();
    for (int p = tid; p < NTOK * 2; p += 256) atomicAdd(&cnt[idx[p]], 1);
    __syncthreads();
    if (tid == 0) {
        int off = 0, nt = 0;
        for (int e = 0; e < E_; e++) {
            seg[e] = off;
            int te = (cnt[e] + 127) >> 7;
            for (int j = 0; j < te; j++) {
                tiles[nt * 2] = e; tiles[nt * 2 + 1] = off + j * 128; nt++;
            }
            off += te * 128;
        }
        for (; nt < MAXTILES; nt++) { tiles[nt * 2] = -1; tiles[nt * 2 + 1] = 0; }
    }
    for (int p = tid; p < NPMAX; p += 256) pair_token[p] = -1;
    __syncthreads();
    for (int p = tid; p < NTOK * 2; p += 256) {
        int e = idx[p];
        int r = atomicAdd(&cur[e], 1);
        int pos = seg[e] + r;
        pair_token[pos] = p >> 1;
        pair_w[pos] = wts[p];
        pos_of[p] = pos;
    }
}

// ---------------- GEMM 1: fused gate/up + activation ----------------
// BM=128, BN=64 per weight, BK=64. XOR-swizzled LDS (rows of 64 shorts;
// phys granule = logical ^ (row&7)), gather fused into staging addresses.
// Wave tile 64x32 per weight; acc = 16 f32x4 = 64 AGPRs (3 waves/SIMD).

__launch_bounds__(256)
__global__ void gemm_act_kernel(const unsigned short* __restrict__ xb,
                                const unsigned short* __restrict__ w1sb,
                                const unsigned short* __restrict__ w3sb,
                                const unsigned short* __restrict__ w1b,
                                const unsigned short* __restrict__ w3b,
                                const int* __restrict__ tiles,
                                const int* __restrict__ pair_token,
                                unsigned short* __restrict__ act) {
    __shared__ __align__(16) unsigned short As[128 * 64];   // 16 KB
    __shared__ __align__(16) unsigned short Bs1[64 * 64];   // 8 KB
    __shared__ __align__(16) unsigned short Bs3[64 * 64];   // 8 KB

    int mt = blockIdx.y;
    const unsigned short *B1, *B3;
    int m0; bool routed;
    if (mt < NSHT) {
        B1 = w1sb; B3 = w3sb; m0 = mt * 128; routed = false;
    } else {
        int e = tiles[(mt - NSHT) * 2];
        if (e < 0) return;
        m0 = NTOK + tiles[(mt - NSHT) * 2 + 1];
        B1 = w1b + (size_t)e * I_ * D_; B3 = w3b + (size_t)e * I_ * D_;
        routed = true;
    }
    int n0 = blockIdx.x * 64;
    int tid = threadIdx.x;
    int lane = tid & 63, wave = tid >> 6;
    int wm = (wave & 1) * 64, wn = (wave >> 1) * 32;
    int l15 = lane & 15, quad = lane >> 4;

    // staging: per inst a wave covers 8 rows x 8 granules (16B each).
    int rl = lane >> 3;                 // row within 8-row group
    int ph = lane & 7;                  // physical granule (LDS position)
    int lg = ph ^ rl;                   // logical granule (row&7 == rl)
    const unsigned short* asrc[4];
#pragma unroll
    for (int j = 0; j < 4; j++) {
        int r = j * 32 + wave * 8 + rl;
        int tok;
        if (routed) { tok = pair_token[m0 - NTOK + r]; if (tok < 0) tok = 0; }
        else tok = m0 + r;
        asrc[j] = xb + (size_t)tok * D_ + lg * 8;
    }
    const unsigned short *b1src[2], *b3src[2];
#pragma unroll
    for (int j = 0; j < 2; j++) {
        int r = j * 32 + wave * 8 + rl;
        b1src[j] = B1 + (size_t)(n0 + r) * D_ + lg * 8;
        b3src[j] = B3 + (size_t)(n0 + r) * D_ + lg * 8;
    }
    unsigned short *ldA[4], *ldB1[2], *ldB3[2];
#pragma unroll
    for (int j = 0; j < 4; j++) ldA[j] = As + (j * 32 + wave * 8) * 64;
#pragma unroll
    for (int j = 0; j < 2; j++) {
        ldB1[j] = Bs1 + (j * 32 + wave * 8) * 64;
        ldB3[j] = Bs3 + (j * 32 + wave * 8) * 64;
    }

    floatx4 acc1[4][2] = {}; floatx4 acc3[4][2] = {};
    int sx = (l15 & 7);   // fragment-read swizzle key

    for (int k0 = 0; k0 < D_; k0 += 64) {
        __syncthreads();
#pragma unroll
        for (int j = 0; j < 4; j++) GLOAD_LDS16(asrc[j] + k0, ldA[j]);
#pragma unroll
        for (int j = 0; j < 2; j++) {
            GLOAD_LDS16(b1src[j] + k0, ldB1[j]);
            GLOAD_LDS16(b3src[j] + k0, ldB3[j]);
        }
        __syncthreads();

#pragma unroll
        for (int kk = 0; kk < 2; kk++) {
            int pq = ((kk * 4 + quad) ^ sx) * 8;
            bf16x8 af[4], b1f[2], b3f[2];
#pragma unroll
            for (int mi = 0; mi < 4; mi++)
                af[mi] = *(const bf16x8*)(As + (wm + mi * 16 + l15) * 64 + pq);
#pragma unroll
            for (int ni = 0; ni < 2; ni++) {
                b1f[ni] = *(const bf16x8*)(Bs1 + (wn + ni * 16 + l15) * 64 + pq);
                b3f[ni] = *(const bf16x8*)(Bs3 + (wn + ni * 16 + l15) * 64 + pq);
            }
#pragma unroll
            for (int mi = 0; mi < 4; mi++)
#pragma unroll
                for (int ni = 0; ni < 2; ni++) {
                    acc1[mi][ni] = __builtin_amdgcn_mfma_f32_16x16x32_bf16(
                        af[mi], b1f[ni], acc1[mi][ni], 0, 0, 0);
                    acc3[mi][ni] = __builtin_amdgcn_mfma_f32_16x16x32_bf16(
                        af[mi], b3f[ni], acc3[mi][ni], 0, 0, 0);
                }
        }
    }

#pragma unroll
    for (int mi = 0; mi < 4; mi++)
#pragma unroll
        for (int ni = 0; ni < 2; ni++) {
            int col = n0 + wn + ni * 16 + l15;
#pragma unroll
            for (int rr = 0; rr < 4; rr++) {
                int row = m0 + wm + mi * 16 + quad * 4 + rr;
                float g = fminf(acc1[mi][ni][rr], 10.f);
                float u = fminf(fmaxf(acc3[mi][ni][rr], -10.f), 10.f);
                float a = g / (1.f + __expf(-g)) * u;
                act[(size_t)row * I_ + col] = f2b(a);
            }
        }
}

// ---------------- GEMM 2: act @ W2, split-K=2, fp32 partials ----------------

__launch_bounds__(256)
__global__ void gemm_out_kernel(const unsigned short* __restrict__ act,
                                const unsigned short* __restrict__ w2sb,
                                const unsigned short* __restrict__ w2b,
                                const int* __restrict__ tiles,
                                float* __restrict__ outp) {
    __shared__ __align__(16) unsigned short As[128 * 64];
    __shared__ __align__(16) unsigned short Bs[64 * 64];

    int mt = blockIdx.y, ks = blockIdx.z;
    int kbase = ks * KS_;
    const unsigned short* B;
    int m0;
    if (mt < NSHT) {
        B = w2sb; m0 = mt * 128;
    } else {
        int e = tiles[(mt - NSHT) * 2];
        if (e < 0) return;
        m0 = NTOK + tiles[(mt - NSHT) * 2 + 1];
        B = w2b + (size_t)e * I_ * D_;
    }
    float* C = outp + (size_t)ks * ROWS * D_;
    int n0 = blockIdx.x * 64;
    int tid = threadIdx.x;
    int lane = tid & 63, wave = tid >> 6;
    int wm = (wave & 1) * 64, wn = (wave >> 1) * 32;
    int l15 = lane & 15, quad = lane >> 4;

    int rl = lane >> 3, ph = lane & 7, lg = ph ^ rl;
    const unsigned short* asrc[4];
#pragma unroll
    for (int j = 0; j < 4; j++)
        asrc[j] = act + (size_t)(m0 + j * 32 + wave * 8 + rl) * I_ + kbase + lg * 8;
    const unsigned short* bsrc[2];
#pragma unroll
    for (int j = 0; j < 2; j++)
        bsrc[j] = B + (size_t)(n0 + j * 32 + wave * 8 + rl) * I_ + kbase + lg * 8;
    unsigned short *ldA[4], *ldB[2];
#pragma unroll
    for (int j = 0; j < 4; j++) ldA[j] = As + (j * 32 + wave * 8) * 64;
#pragma unroll
    for (int j = 0; j < 2; j++) ldB[j] = Bs + (j * 32 + wave * 8) * 64;

    floatx4 acc[4][2] = {};
    int sx = (l15 & 7);

    for (int k0 = 0; k0 < KS_; k0 += 64) {
        __syncthreads();
#pragma unroll
        for (int j = 0; j < 4; j++) GLOAD_LDS16(asrc[j] + k0, ldA[j]);
#pragma unroll
        for (int j = 0; j < 2; j++) GLOAD_LDS16(bsrc[j] + k0, ldB[j]);
        __syncthreads();

#pragma unroll
        for (int kk = 0; kk < 2; kk++) {
            int pq = ((kk * 4 + quad) ^ sx) * 8;
            bf16x8 af[4], bf[2];
#pragma unroll
            for (int mi = 0; mi < 4; mi++)
                af[mi] = *(const bf16x8*)(As + (wm + mi * 16 + l15) * 64 + pq);
#pragma unroll
            for (int ni = 0; ni < 2; ni++)
                bf[ni] = *(const bf16x8*)(Bs + (wn + ni * 16 + l15) * 64 + pq);
#pragma unroll
            for (int mi = 0; mi < 4; mi++)
#pragma unroll
                for (int ni = 0; ni < 2; ni++)
                    acc[mi][ni] = __builtin_amdgcn_mfma_f32_16x16x32_bf16(
                        af[mi], bf[ni], acc[mi][ni], 0, 0, 0);
        }
    }

#pragma unroll
    for (int mi = 0; mi < 4; mi++)
#pragma unroll
        for (int ni = 0; ni < 2; ni++) {
            int col = n0 + wn + ni * 16 + l15;
#pragma unroll
            for (int rr = 0; rr < 4; rr++) {
                int row = m0 + wm + mi * 16 + quad * 4 + rr;
                C[(size_t)row * D_ + col] = acc[mi][ni][rr];
            }
        }
}

// ---------------- combine: sum split-K partials + weighted routed -----------

__global__ void combine_kernel(const float* __restrict__ outp,
                               const int* __restrict__ pos_of,
                               const float* __restrict__ pair_w,
                               float* __restrict__ out) {
    int gid = blockIdx.x * 256 + threadIdx.x;
    int t = gid / (D_ / 4);
    int j = (gid % (D_ / 4)) * 4;
    int p0 = pos_of[2 * t], p1 = pos_of[2 * t + 1];
    float w0 = pair_w[p0], w1 = pair_w[p1];
    float a0 = 0.f, a1 = 0.f, a2 = 0.f, a3 = 0.f;
#pragma unroll
    for (int ks = 0; ks < SPLITK; ks++) {
        const float* P = outp + (size_t)ks * ROWS * D_;
        float4 a = *(const float4*)(P + (size_t)t * D_ + j);
        float4 b = *(const float4*)(P + (size_t)(NTOK + p0) * D_ + j);
        float4 c = *(const float4*)(P + (size_t)(NTOK + p1) * D_ + j);
        a0 += a.x + w0 * b.x + w1 * c.x;
        a1 += a.y + w0 * b.y + w1 * c.y;
        a2 += a.z + w0 * b.z + w1 * c.z;
        a3 += a.w + w0 * b.w + w1 * c.w;
    }
    float4 o; o.x = a0; o.y = a1; o.z = a2; o.w = a3;
    *(float4*)(out + (size_t)t * D_ + j) = o;
}

// ---------------- launch ----------------

extern "C" void kernel_launch(void* const* d_in, const int* in_sizes, int n_in,
                              void* d_out, int out_size, void* d_ws, size_t ws_size,
                              hipStream_t stream) {
    (void)in_sizes; (void)n_in; (void)out_size; (void)ws_size;
    const float* x   = (const float*)d_in[0];
    const float* gw  = (const float*)d_in[2];
    const float* gb  = (const float*)d_in[3];
    const float* w1  = (const float*)d_in[4];
    const float* w2  = (const float*)d_in[5];
    const float* w3  = (const float*)d_in[6];
    const float* w1s = (const float*)d_in[7];
    const float* w2s = (const float*)d_in[8];
    const float* w3s = (const float*)d_in[9];
    float* out = (float*)d_out;

    char* ws = (char*)d_ws;
    size_t off = 0;
    auto alloc = [&](size_t bytes) {
        size_t o = (off + 255) & ~(size_t)255;
        off = o + bytes;
        return (void*)(ws + o);
    };
    unsigned short* xb   = (unsigned short*)alloc((size_t)NTOK * D_ * 2);
    unsigned short* w1b  = (unsigned short*)alloc((size_t)E_ * I_ * D_ * 2);
    unsigned short* w3b  = (unsigned short*)alloc((size_t)E_ * I_ * D_ * 2);
    unsigned short* w2b  = (unsigned short*)alloc((size_t)E_ * I_ * D_ * 2);
    unsigned short* w1sb = (unsigned short*)alloc((size_t)I_ * D_ * 2);
    unsigned short* w3sb = (unsigned short*)alloc((size_t)I_ * D_ * 2);
    unsigned short* w2sb = (unsigned short*)alloc((size_t)I_ * D_ * 2);
    unsigned short* act  = (unsigned short*)alloc((size_t)ROWS * I_ * 2);
    float* outp = (float*)alloc((size_t)SPLITK * ROWS * D_ * 4);
    int*   idx  = (int*)alloc((size_t)NTOK * 2 * 4);
    float* wts  = (float*)alloc((size_t)NTOK * 2 * 4);
    int*   ptok = (int*)alloc((size_t)NPMAX * 4);
    float* pw   = (float*)alloc((size_t)NPMAX * 4);
    int*   posf = (int*)alloc((size_t)NTOK * 2 * 4);
    int*   tls  = (int*)alloc((size_t)MAXTILES * 2 * 4);

    prep_kernel<<<17600, 256, 0, stream>>>(x, gw, gb, w1, w2, w3, w1s, w2s, w3s,
                                           xb, w1b, w3b, w2b, w1sb, w3sb, w2sb,
                                           idx, wts);
    route_build_kernel<<<1, 256, 0, stream>>>(idx, wts, ptok, pw, posf, tls);
    gemm_act_kernel<<<dim3(I_ / 64, NSHT + MAXTILES), 256, 0, stream>>>(
        xb, w1sb, w3sb, w1b, w3b, tls, ptok, act);
    gemm_out_kernel<<<dim3(D_ / 64, NSHT + MAXTILES, SPLITK), 256, 0, stream>>>(
        act, w2sb, w2b, tls, outp);
    combine_kernel<<<NTOK * (D_ / 4) / 256, 256, 0, stream>>>(outp, posf, pw, out);
}